// Round 1
// baseline (442.092 us; speedup 1.0000x reference)
//
#include <hip/hip_runtime.h>

// VDPDropout: B=16, HW=16 (HW2=256), C=64
//   mu_in    [16,16,16,64]     f32   (262144)
//   Sigma_in [16,256,256,64]   f32   (67108864)
//   drop_mask[16,16,16,64]     f32   (262144)
// outputs (concat in d_out): mu_out (262144) then Sigma_out (67108864), f32.

#define MU_N      262144      // B*HW2*C
#define MU_N4     65536       // MU_N / 4
#define SIG_N4    16777216LL  // 67108864 / 4
#define SCALE     1.25f
#define SCALE2    1.5625f
#define DROP_P    0.2f

// Kernel A: mu_out = keep ? mu_in*1.25 : 0 ; mask = (mu_out != 0) ? 1 : 0
__global__ void __launch_bounds__(256) vdp_mu_kernel(
    const float4* __restrict__ mu_in,
    const float4* __restrict__ drop_mask,
    float4* __restrict__ mu_out,
    float4* __restrict__ mask_out)
{
    int i = blockIdx.x * blockDim.x + threadIdx.x;
    if (i >= MU_N4) return;
    float4 m = mu_in[i];
    float4 d = drop_mask[i];
    float4 o, f;
    o.x = (d.x >= DROP_P) ? m.x * SCALE : 0.0f;
    o.y = (d.y >= DROP_P) ? m.y * SCALE : 0.0f;
    o.z = (d.z >= DROP_P) ? m.z * SCALE : 0.0f;
    o.w = (d.w >= DROP_P) ? m.w * SCALE : 0.0f;
    f.x = (o.x != 0.0f) ? 1.0f : 0.0f;
    f.y = (o.y != 0.0f) ? 1.0f : 0.0f;
    f.z = (o.z != 0.0f) ? 1.0f : 0.0f;
    f.w = (o.w != 0.0f) ? 1.0f : 0.0f;
    mu_out[i] = o;
    mask_out[i] = f;
}

// Kernel B: Sigma_out[b,i,j,c] = (1.5625*Sigma_in[b,i,j,c]) * m[b,i,c] * m[b,j,c]
// float4 over innermost C dim (C/4 = 16 quads per (b,i,j)).
__global__ void __launch_bounds__(256) vdp_sigma_kernel(
    const float4* __restrict__ sigma_in,
    const float4* __restrict__ mask,
    float4* __restrict__ sigma_out)
{
    long long stride = (long long)gridDim.x * blockDim.x;
    for (long long q = (long long)blockIdx.x * blockDim.x + threadIdx.x;
         q < SIG_N4; q += stride) {
        int c4 = (int)(q & 15);
        long long t = q >> 4;
        int j = (int)(t & 255);
        t >>= 8;
        int i = (int)(t & 255);
        int b = (int)(t >> 8);

        float4 s  = sigma_in[q];
        float4 fi = mask[(((b << 8) | i) << 4) | c4];
        float4 fj = mask[(((b << 8) | j) << 4) | c4];
        float4 o;
        o.x = (SCALE2 * s.x) * fi.x * fj.x;
        o.y = (SCALE2 * s.y) * fi.y * fj.y;
        o.z = (SCALE2 * s.z) * fi.z * fj.z;
        o.w = (SCALE2 * s.w) * fi.w * fj.w;
        sigma_out[q] = o;
    }
}

extern "C" void kernel_launch(void* const* d_in, const int* in_sizes, int n_in,
                              void* d_out, int out_size, void* d_ws, size_t ws_size,
                              hipStream_t stream) {
    const float4* mu_in     = (const float4*)d_in[0];
    const float4* sigma_in  = (const float4*)d_in[1];
    const float4* drop_mask = (const float4*)d_in[2];

    float* out      = (float*)d_out;
    float4* mu_out    = (float4*)out;               // first 262144 floats
    float4* sigma_out = (float4*)(out + MU_N);      // next 67108864 floats (16B aligned)
    float4* mask      = (float4*)d_ws;              // 1 MB scratch

    // Kernel A: 65536 quads / 256 = 256 blocks
    vdp_mu_kernel<<<MU_N4 / 256, 256, 0, stream>>>(mu_in, drop_mask, mu_out, mask);

    // Kernel B: grid-stride, 2048 blocks x 256 threads
    vdp_sigma_kernel<<<2048, 256, 0, stream>>>(sigma_in, mask, sigma_out);
}